// Round 10
// baseline (54.261 us; speedup 1.0000x reference)
//
#include <hip/hip_runtime.h>
#include <math.h>
#include <stdint.h>

#define IN_C 64
#define OUT_C 128
#define H 56
#define W 56
#define NB 32
#define HW (H*W)
#define KK 576          // IN_C*9
#define EPS 1e-12f
#define PH 58           // padded rows
#define PW 66           // padded cols in xcl (only 0..57 staged/used by conv)

typedef _Float16 half8 __attribute__((ext_vector_type(8)));
typedef float f32x4 __attribute__((ext_vector_type(4)));
typedef unsigned int u32;
typedef const u32 __attribute__((address_space(1)))* gp_t;
typedef u32 __attribute__((address_space(3)))* sp_t;

// ---------------- kernel 1: transpose to channels-last padded fp16 ----------
// xcl[n][pr][pc][ c ^ ((pc&7)<<3) ]; also s[n][h][w] = sum_c x^2 (fused).
__global__ __launch_bounds__(256) void k_xpose(const float* __restrict__ x,
                                               _Float16* __restrict__ xcl,
                                               float* __restrict__ s) {
    __shared__ float lds[64][59];
    int n = blockIdx.y, pr = blockIdx.x;
    int tid = threadIdx.x;
    int h = pr - 1;
    bool rowz = (h < 0 || h >= H);
    {
        int w = tid & 63, c4 = tid >> 6;
        if (!rowz && w < 56) {
#pragma unroll
            for (int cg = 0; cg < 16; ++cg) {
                int c = cg * 4 + c4;
                lds[c][w] = x[((size_t)(n * IN_C + c)) * HW + h * W + w];
            }
        }
    }
    __syncthreads();
    int c = tid & 63, pg = tid >> 6;
    _Float16* dst = xcl + ((size_t)n * PH + pr) * PW * IN_C;
#pragma unroll
    for (int pcg = 0; pcg < 15; ++pcg) {
        int pc = pcg * 4 + pg;          // only cols 0..57 are consumed
        if (pc >= 58) break;
        int w = pc - 1;
        bool valid = (!rowz && (unsigned)w < W);
        float val = valid ? lds[c][w] : 0.f;
        dst[(size_t)pc * IN_C + (c ^ ((pc & 7) << 3))] = (_Float16)val;
        float sq = val * val;
#pragma unroll
        for (int off = 32; off > 0; off >>= 1) sq += __shfl_xor(sq, off);
        if (valid && c == 0) s[(size_t)n * HW + h * W + w] = sq;
    }
}

// ---------------- kernel 2: 3x3 neighborhood sum -> 1/x_norm (4 px/thread) --
__global__ __launch_bounds__(256) void k_xnorm(const float* __restrict__ s,
                                               const float* __restrict__ q,
                                               float* __restrict__ inv_xn) {
    int t = blockIdx.x * 256 + threadIdx.x;
    if (t >= NB * HW / 4) return;
    int n = t / (HW / 4);
    int rem = t - n * (HW / 4);
    int p0 = rem * 4;
    int h = p0 / W, w0 = p0 - h * W;
    float q2 = q[0] * 0.01f;
    q2 = q2 * q2;
    const float* sp = s + (size_t)n * HW;
    float a0 = 0.f, a1 = 0.f, a2 = 0.f, a3 = 0.f;
#pragma unroll
    for (int dy = -1; dy <= 1; ++dy) {
        int y = h + dy;
        if ((unsigned)y >= H) continue;
        const float* row = sp + y * W;
        float4 m = *(const float4*)(row + w0);
        float lft = (w0 > 0) ? row[w0 - 1] : 0.f;
        float rgt = (w0 + 4 < W) ? row[w0 + 4] : 0.f;
        a0 += lft + m.x + m.y;
        a1 += m.x + m.y + m.z;
        a2 += m.y + m.z + m.w;
        a3 += m.z + m.w + rgt;
    }
    float4 res;
    res.x = 1.f / (sqrtf(a0 + EPS) + q2);
    res.y = 1.f / (sqrtf(a1 + EPS) + q2);
    res.z = 1.f / (sqrtf(a2 + EPS) + q2);
    res.w = 1.f / (sqrtf(a3 + EPS) + q2);
    *(float4*)(inv_xn + (size_t)n * HW + p0) = res;
}

// ---------------- kernel 3: weight prep, B-fragment-native layout ------------
// wt2[l][kc][v][cc]: kc = k*4+kg (k-chunk of 8 channels), so one B-frag load
// is lanes (kg,l15) -> 4 x 256B dense chunks (fully coalesced, L1-friendly).
// value = w[v][c][l] / w_norm[v], c = (kc<<3)+cc.  e[v] = (p[v]/10)^2.
__global__ __launch_bounds__(64) void k_wprep(const float* __restrict__ w,
                                              const float* __restrict__ p,
                                              const float* __restrict__ q,
                                              _Float16* __restrict__ wt2,
                                              float* __restrict__ e) {
    int v = blockIdx.x;
    int lane = threadIdx.x;          // lane = c
    const float* wv = w + v * KK;
    float acc = 0.f;
#pragma unroll
    for (int j = 0; j < 9; ++j) {
        float t = wv[lane * 9 + j];
        acc += t * t;
    }
#pragma unroll
    for (int off = 32; off > 0; off >>= 1) acc += __shfl_xor(acc, off);
    float q2 = q[0] * 0.01f;
    q2 = q2 * q2;
    float inv = 1.f / (sqrtf(acc + EPS) + q2);
    int kc = lane >> 3;              // 0..7
    int cc = lane & 7;
#pragma unroll
    for (int l = 0; l < 9; ++l) {
        wt2[(((size_t)l * 8 + kc) * OUT_C + v) * 8 + cc] =
            (_Float16)(wv[lane * 9 + l] * inv);
    }
    if (lane == 0) e[v] = p[v] * p[v] * 0.01f;
}

// ---------------- kernel 4: MFMA conv, barrier-free, B-from-L2 ---------------
// Block: 256 thr (4 waves) = 4 rows x 64 cols x 64 filters (vh half).
// x tile (6 rows, 45.5KB static LDS) staged via global_load_lds, ONE barrier,
// then 9 unrolled taps: A-frags from LDS, B-frags straight from L2/L1 in the
// dense wt2 layout. No w-LDS, no dbuf, no in-loop barriers -> waves drift.
// 3 blocks/CU by LDS; ~170 VGPR cap leaves room for cross-tap b-load hoist.
__global__ __launch_bounds__(256, 3) void k_conv_mfma(
    const _Float16* __restrict__ xcl,   // [NB][PH][PW][64] swizzled
    const _Float16* __restrict__ wt2,   // [9][8][128][8]
    const float* __restrict__ inv_xn,   // [NB][HW]
    const float* __restrict__ e,        // [128]
    float* __restrict__ out)            // [NB][128][HW]
{
    __shared__ __align__(16) char xls[46592];   // 6*58*64*2 = 44544 + OOB slack

    int tid = threadIdx.x;
    int wv = tid >> 6;               // wave = row_rel 0..3
    int lane = tid & 63;
    int l15 = lane & 15;
    int kg = lane >> 4;              // 0..3

    // bijective XCD swizzle over 896 blocks (112 per XCD)
    int flat = (blockIdx.z * 2 + blockIdx.y) * 14 + blockIdx.x;
    int sw = (flat & 7) * 112 + (flat >> 3);
    int n = sw / 28;
    int rem = sw - n * 28;
    int vh = rem / 14;
    int r0 = (rem - vh * 14) * 4;

    // ---- stage x tile: 6 rows x 58 cols x 64c (2784 16B chunks)
    {
        const char* xsrc = (const char*)(xcl + ((size_t)n * PH + r0) * PW * IN_C);
#pragma unroll
        for (int i = 0; i < 11; ++i) {
            int j = i * 256 + tid;
            if (j < 2784) {
                int row = j / 464;
                int off = j - row * 464;
                __builtin_amdgcn_global_load_lds(
                    (gp_t)(xsrc + row * (PW * IN_C * 2) + off * 16),
                    (sp_t)(xls + (i * 256 + wv * 64) * 16), 16, 0, 0);
            }
        }
    }
    __syncthreads();                 // the only barrier

    f32x4 acc[4][4];
#pragma unroll
    for (int mt = 0; mt < 4; ++mt)
#pragma unroll
        for (int vt = 0; vt < 4; ++vt) acc[mt][vt] = (f32x4){0.f, 0.f, 0.f, 0.f};

#pragma unroll
    for (int l = 0; l < 9; ++l) {
        int di = l / 3, dj = l % 3;
        int pc0 = l15 + dj;
        const char* xb = xls + ((wv + di) * 58 + pc0) * 128;
        int xkey = (pc0 & 7) << 4;
        // B-frags: dense global loads (4 x 256B per instr), L1/L2-hot
        const half8* wB = (const half8*)(wt2 + (size_t)l * 8 * OUT_C * 8);
        half8 b[2][4];
#pragma unroll
        for (int k = 0; k < 2; ++k)
#pragma unroll
            for (int vt = 0; vt < 4; ++vt)
                b[k][vt] = wB[(k * 4 + kg) * OUT_C / 1 + vh * 64 + vt * 16 + l15];
        half8 a[2][4];
#pragma unroll
        for (int k = 0; k < 2; ++k)
#pragma unroll
            for (int mt = 0; mt < 4; ++mt)
                a[k][mt] = *(const half8*)(
                    xb + mt * 2048 + ((k * 64 + kg * 16) ^ xkey));

        __builtin_amdgcn_s_setprio(1);
#pragma unroll
        for (int k = 0; k < 2; ++k)
#pragma unroll
            for (int vt = 0; vt < 4; ++vt)
#pragma unroll
                for (int mt = 0; mt < 4; ++mt)
                    acc[mt][vt] = __builtin_amdgcn_mfma_f32_16x16x32_f16(
                        a[k][mt], b[k][vt], acc[mt][vt], 0, 0, 0);
        __builtin_amdgcn_s_setprio(0);
    }

    // ---- epilogue: lane holds cols mt*16+kg*4..+3 for v = vh*64+vt*16+l15
    int r = r0 + wv;
    const float* ixrow = inv_xn + (size_t)n * HW + r * W;
#pragma unroll
    for (int mt = 0; mt < 4; ++mt) {
        int col0 = mt * 16 + kg * 4;
        if (col0 >= W) continue;         // garbage cols 56..63
        float4 ixn = *(const float4*)(ixrow + col0);
        const float* ixp = &ixn.x;
#pragma unroll
        for (int vt = 0; vt < 4; ++vt) {
            int v = vh * 64 + vt * 16 + l15;
            float ev = e[v];
            float4 res;
            float* rp = &res.x;
            if (fabsf(ev - 2.0f) < 1e-4f) {
#pragma unroll
                for (int j = 0; j < 4; ++j) {
                    float z = acc[mt][vt][j] * ixp[j];
                    float mag = fabsf(z) + EPS;
                    rp[j] = copysignf(mag * mag, z);
                }
            } else {
#pragma unroll
                for (int j = 0; j < 4; ++j) {
                    float z = acc[mt][vt][j] * ixp[j];
                    float mag = fabsf(z) + EPS;
                    float pw = exp2f(ev * log2f(mag));
                    rp[j] = copysignf(pw, z);
                }
            }
            *(float4*)(out + ((size_t)n * OUT_C + v) * HW + r * W + col0) = res;
        }
    }
}

// ---------------- launch ----------------------------------------------------
extern "C" void kernel_launch(void* const* d_in, const int* in_sizes, int n_in,
                              void* d_out, int out_size, void* d_ws, size_t ws_size,
                              hipStream_t stream) {
    const float* x = (const float*)d_in[0];
    const float* w = (const float*)d_in[1];
    const float* p = (const float*)d_in[2];
    const float* q = (const float*)d_in[3];
    float* out = (float*)d_out;

    char* ws = (char*)d_ws;
    float*    s      = (float*)ws;                              // 100352 f
    float*    inv_xn = (float*)(ws + 401408);                   // 100352 f
    float*    e      = (float*)(ws + 802816);                   // 128 f
    _Float16* wt2    = (_Float16*)(ws + 803328);                // 9*8*128*8 h
    _Float16* xcl    = (_Float16*)(ws + 950784);                // 32*58*66*64 h

    k_xpose<<<dim3(PH, NB), dim3(256), 0, stream>>>(x, xcl, s);
    k_xnorm<<<dim3(NB * HW / 4 / 256), dim3(256), 0, stream>>>(s, q, inv_xn);
    k_wprep<<<dim3(OUT_C), dim3(64), 0, stream>>>(w, p, q, wt2, e);
    k_conv_mfma<<<dim3(14, 2, NB), dim3(256), 0, stream>>>(
        xcl, wt2, inv_xn, e, out);
}